// Round 8
// baseline (603.943 us; speedup 1.0000x reference)
//
#include <hip/hip_runtime.h>
#include <math.h>

#define M_TOK 100352   // 8*112*112 tokens
#define NHEAD 6

typedef unsigned short u16;
typedef __attribute__((ext_vector_type(8))) short bf16x8;
typedef __attribute__((ext_vector_type(4))) float f32x4;
typedef __attribute__((ext_vector_type(4))) unsigned int u32x4;

__device__ inline u16 f2bf(float f) {
    union { float f; unsigned int i; } v; v.f = f;
    unsigned int r = v.i + 0x7fffu + ((v.i >> 16) & 1u);
    return (u16)(r >> 16);
}

// ---------------------------------------------------------------------------
// Merged prep: [0,882) cast weights; [882,1170) fold conv w; [1170,1218) bias.
// ---------------------------------------------------------------------------
__global__ __launch_bounds__(256) void prep_kernel(const float* __restrict__ qkvw,
        const float* __restrict__ projw, const float* __restrict__ f1w,
        const float* __restrict__ f2w, const float* __restrict__ outw,
        const float* __restrict__ up_w, const float* __restrict__ rel,
        u16* __restrict__ Wh, u16* __restrict__ Wc, float* __restrict__ BT) {
    int bid = blockIdx.x;
    if (bid < 882) {
        int i = bid * 256 + threadIdx.x;
        if (i < 55296) Wh[i] = f2bf(qkvw[i]);
        else if (i < 73728) Wh[i] = f2bf(projw[i - 55296]);
        else if (i < 147456) Wh[i] = f2bf(f1w[i - 73728]);
        else if (i < 221184) Wh[i] = f2bf(f2w[i - 147456]);
        else if (i < 225792) Wh[i] = f2bf(outw[i - 221184]);
        return;
    }
    if (bid < 1170) {
        int idx = (bid - 882) * 256 + threadIdx.x;
        if (idx >= 96 * 4 * 192) return;
        int c2 = idx / 768;
        int rem = idx - c2 * 768;
        int p = rem / 192;
        int ci = rem - p * 192;
        int po = p >> 1, pw = p & 1;
        const float* w = up_w + (c2 * 192 + ci) * 9;
        float w9[9];
#pragma unroll
        for (int k = 0; k < 9; k++) w9[k] = w[k];
        float r0[3], r1[3];
#pragma unroll
        for (int kw = 0; kw < 3; kw++) {
            if (po == 0) { r0[kw] = w9[kw];              r1[kw] = w9[3 + kw] + w9[6 + kw]; }
            else         { r0[kw] = w9[kw] + w9[3 + kw]; r1[kw] = w9[6 + kw]; }
        }
        float o00, o01, o10, o11;
        if (pw == 0) { o00 = r0[0];         o01 = r0[1] + r0[2]; o10 = r1[0];         o11 = r1[1] + r1[2]; }
        else         { o00 = r0[0] + r0[1]; o01 = r0[2];         o10 = r1[0] + r1[1]; o11 = r1[2]; }
        size_t base = ((size_t)p * 4 * 96 + c2) * 192 + ci;
        Wc[base + 0 * 96 * 192] = f2bf(o00);
        Wc[base + 1 * 96 * 192] = f2bf(o01);
        Wc[base + 2 * 96 * 192] = f2bf(o10);
        Wc[base + 3 * 96 * 192] = f2bf(o11);
        return;
    }
    {
        int blkid = bid - 1170;                // blk*24 + type*6 + head
        int blk = blkid / 24;
        int rem = blkid - blk * 24;
        int type = rem / 6, head = rem - (rem / 6) * 6;
        const float* relp = rel + blk * 1014;
        bool shift = (blk == 1);
        for (int i = threadIdx.x; i < 4096; i += 256) {
            int a = i >> 6, k = i & 63;
            float v;
            if (k >= 49) v = -1e30f;
            else if (a >= 49) v = 0.f;
            else {
                int ah = (a * 37) >> 8, aw = a - ah * 7;
                int kh = (k * 37) >> 8, kw = k - kh * 7;
                v = relp[((ah - kh + 6) * 13 + (aw - kw + 6)) * 6 + head];
                if (shift) {
                    int lha = (type & 2) ? (ah < 4 ? 1 : 2) : 0;
                    int lwa = (type & 1) ? (aw < 4 ? 1 : 2) : 0;
                    int lhk = (type & 2) ? (kh < 4 ? 1 : 2) : 0;
                    int lwk = (type & 1) ? (kw < 4 ? 1 : 2) : 0;
                    if (lha != lhk || lwa != lwk) v -= 100.f;
                }
            }
            BT[(size_t)blkid * 4096 + i] = v;
        }
    }
}

// ---------------------------------------------------------------------------
// x [b][192][56][56] f32 -> xT [b][3136][192] bf16 (XOR-swizzled LDS).
// ---------------------------------------------------------------------------
__global__ __launch_bounds__(256) void transpose_kernel(const float* __restrict__ x,
                                                        u16* __restrict__ xT) {
    __shared__ unsigned int ts[64 * 96];
    int b = blockIdx.y;
    int pix0 = blockIdx.x * 64;
    int tid = threadIdx.x;
    int p = tid & 63, dg = tid >> 6;
    const float* xb = x + (size_t)b * 192 * 3136 + pix0 + p;
    for (int d = dg; d < 96; d += 4) {
        float v0 = xb[(size_t)(2 * d) * 3136];
        float v1 = xb[(size_t)(2 * d + 1) * 3136];
        unsigned int pk = ((unsigned int)f2bf(v1) << 16) | (unsigned int)f2bf(v0);
        ts[p * 96 + ((d & ~31) | ((d & 31) ^ (p & 31)))] = pk;
    }
    __syncthreads();
    for (int i = tid; i < 1536; i += 256) {
        int pp = i / 24, c = i - pp * 24;
        unsigned int r[4];
#pragma unroll
        for (int j = 0; j < 4; j++) {
            int d = c * 4 + j;
            r[j] = ts[pp * 96 + ((d & ~31) | ((d & 31) ^ (pp & 31)))];
        }
        u32x4 v = {r[0], r[1], r[2], r[3]};
        *(u32x4*)&xT[((size_t)b * 3136 + pix0 + pp) * 192 + c * 8] = v;
    }
}

// ---------------------------------------------------------------------------
// Implicit-GEMM conv via MFMA: xs staged ONCE, W fragments direct from global
// (L2-resident), 2 barriers total. BN + ReLU -> T f32 + fused LN1 -> XBh bf16.
// ---------------------------------------------------------------------------
__global__ __launch_bounds__(256) void conv_mfma(const u16* __restrict__ xT,
        const u16* __restrict__ Wc, const float* __restrict__ up_b,
        const float* __restrict__ bn_g, const float* __restrict__ bn_b,
        const float* __restrict__ bn_m, const float* __restrict__ bn_v,
        const float* __restrict__ lg, const float* __restrict__ lb,
        float* __restrict__ T, u16* __restrict__ XBh) {
    __shared__ u16 xs[81 * 200];
    __shared__ float2 parts[128];
    int tile = blockIdx.x, p = blockIdx.y, b = blockIdx.z;
    int po = p >> 1, pw = p & 1;
    int a0 = (tile / 7) * 8, b0 = (tile % 7) * 8;
    int rro = a0 - 1 + po, cco = b0 - 1 + pw;
    int tid = threadIdx.x;
    int w = tid >> 6, lane = tid & 63, quad = lane >> 4, l16 = lane & 15;
    int mbase = (w & 1) * 32;
    int nt0 = (w >> 1) * 3;
    int half = w >> 1;

    for (int i = tid; i < 1944; i += 256) {
        int pix = i / 24, c = i - pix * 24;
        int rr = pix / 9, cc = pix - rr * 9;
        int gr = rro + rr, gc = cco + cc;
        u32x4 v = {0u, 0u, 0u, 0u};
        if ((unsigned)gr < 56u && (unsigned)gc < 56u)
            v = *(const u32x4*)&xT[((size_t)b * 3136 + gr * 56 + gc) * 192 + c * 8];
        *(u32x4*)&xs[pix * 200 + c * 8] = v;
    }

    f32x4 acc[2][3];
#pragma unroll
    for (int mi = 0; mi < 2; mi++)
#pragma unroll
        for (int ni = 0; ni < 3; ni++) acc[mi][ni] = f32x4{0.f, 0.f, 0.f, 0.f};

    int aoffp[2];
#pragma unroll
    for (int mi = 0; mi < 2; mi++) {
        int pixel = mbase + mi * 16 + l16;
        aoffp[mi] = ((pixel >> 3) * 9 + (pixel & 7)) * 200;
    }
    // W row bases for this wave's 3 n-tiles (parity p)
    const u16* wrow[3];
#pragma unroll
    for (int ni = 0; ni < 3; ni++)
        wrow[ni] = Wc + ((size_t)p * 4 * 96 + (nt0 + ni) * 16 + l16) * 192 + quad * 8;

    __syncthreads();

    for (int tap = 0; tap < 4; tap++) {
        int di = tap >> 1, dj = tap & 1;
        int tsh = (di * 9 + dj) * 200;
        size_t wtap = (size_t)tap * 96 * 192;
#pragma unroll
        for (int kc = 0; kc < 2; kc++) {
#pragma unroll
            for (int kk = 0; kk < 3; kk++) {
                bf16x8 af[2], bfr[3];
#pragma unroll
                for (int mi = 0; mi < 2; mi++)
                    af[mi] = *(const bf16x8*)&xs[aoffp[mi] + tsh + kc * 96 + kk * 32 + quad * 8];
#pragma unroll
                for (int ni = 0; ni < 3; ni++)
                    bfr[ni] = *(const bf16x8*)(wrow[ni] + wtap + kc * 96 + kk * 32);
#pragma unroll
                for (int mi = 0; mi < 2; mi++)
#pragma unroll
                    for (int ni = 0; ni < 3; ni++)
                        acc[mi][ni] = __builtin_amdgcn_mfma_f32_16x16x32_bf16(
                            af[mi], bfr[ni], acc[mi][ni], 0, 0, 0);
            }
        }
    }

    // BN + ReLU -> T (keep values in acc for LN)
#pragma unroll
    for (int ni = 0; ni < 3; ni++) {
        int c2 = (nt0 + ni) * 16 + l16;
        float sc = bn_g[c2] * rsqrtf(bn_v[c2] + 1e-5f);
        float sh = (up_b[c2] - bn_m[c2]) * sc + bn_b[c2];
#pragma unroll
        for (int mi = 0; mi < 2; mi++) {
#pragma unroll
            for (int reg = 0; reg < 4; reg++) {
                int pixel = mbase + mi * 16 + quad * 4 + reg;
                int pr = pixel >> 3, pc = pixel & 7;
                int oh = 2 * (a0 + pr) + po, ow = 2 * (b0 + pc) + pw;
                size_t tok = (size_t)b * 12544 + oh * 112 + ow;
                float v = fmaxf(acc[mi][ni][reg] * sc + sh, 0.f);
                acc[mi][ni][reg] = v;
                T[tok * 96 + c2] = v;
            }
        }
    }

    // fused LN over channels
    float sA[2][4], qA[2][4];
#pragma unroll
    for (int mi = 0; mi < 2; mi++)
#pragma unroll
        for (int reg = 0; reg < 4; reg++) {
            float s = acc[mi][0][reg] + acc[mi][1][reg] + acc[mi][2][reg];
            float q = acc[mi][0][reg] * acc[mi][0][reg] + acc[mi][1][reg] * acc[mi][1][reg]
                    + acc[mi][2][reg] * acc[mi][2][reg];
#pragma unroll
            for (int d = 1; d < 16; d <<= 1) {
                s += __shfl_xor(s, d, 64);
                q += __shfl_xor(q, d, 64);
            }
            sA[mi][reg] = s; qA[mi][reg] = q;
        }
    if (l16 == 0) {
#pragma unroll
        for (int mi = 0; mi < 2; mi++)
#pragma unroll
            for (int reg = 0; reg < 4; reg++) {
                int pixel = mbase + mi * 16 + quad * 4 + reg;
                parts[pixel * 2 + half] = make_float2(sA[mi][reg], qA[mi][reg]);
            }
    }
    __syncthreads();
    float gcl[3], bcl[3];
#pragma unroll
    for (int ni = 0; ni < 3; ni++) {
        int c2 = (nt0 + ni) * 16 + l16;
        gcl[ni] = lg[c2]; bcl[ni] = lb[c2];
    }
#pragma unroll
    for (int mi = 0; mi < 2; mi++)
#pragma unroll
        for (int reg = 0; reg < 4; reg++) {
            int pixel = mbase + mi * 16 + quad * 4 + reg;
            float2 oth = parts[pixel * 2 + (half ^ 1)];
            float ts_ = sA[mi][reg] + oth.x, tq = qA[mi][reg] + oth.y;
            float mean = ts_ * (1.f / 96.f);
            float var = tq * (1.f / 96.f) - mean * mean;
            float rstd = rsqrtf(var + 1e-5f);
            int pr = pixel >> 3, pc = pixel & 7;
            int oh = 2 * (a0 + pr) + po, ow = 2 * (b0 + pc) + pw;
            size_t tok = (size_t)b * 12544 + oh * 112 + ow;
#pragma unroll
            for (int ni = 0; ni < 3; ni++) {
                int c2 = (nt0 + ni) * 16 + l16;
                XBh[tok * 96 + c2] = f2bf((acc[mi][ni][reg] - mean) * rstd * gcl[ni] + bcl[ni]);
            }
        }
}

// ---------------------------------------------------------------------------
// LDS-free bf16 GEMM (K=96): C = Xh @ W^T + bias [,GELU] -> bf16.
// ---------------------------------------------------------------------------
template <int EPI>
__global__ __launch_bounds__(256) void gemm_act(const u16* __restrict__ Xh,
        const u16* __restrict__ W, const float* __restrict__ bias,
        u16* __restrict__ Cout, int N) {
    int tid = threadIdx.x;
    int w = tid >> 6, lane = tid & 63, quad = lane >> 4, l16 = lane & 15;
    int mh = w & 1, nh = w >> 1;
    int n0 = blockIdx.x * 96;
    size_t m0 = (size_t)blockIdx.y * 128;

    bf16x8 af[3][3], bf[4][3];
#pragma unroll
    for (int ni = 0; ni < 3; ni++)
#pragma unroll
        for (int kk = 0; kk < 3; kk++)
            af[ni][kk] = *(const bf16x8*)&W[(size_t)(n0 + nh * 48 + ni * 16 + l16) * 96 + kk * 32 + quad * 8];
#pragma unroll
    for (int mi = 0; mi < 4; mi++)
#pragma unroll
        for (int kk = 0; kk < 3; kk++)
            bf[mi][kk] = *(const bf16x8*)&Xh[(m0 + mh * 64 + mi * 16 + l16) * 96 + kk * 32 + quad * 8];

    f32x4 acc[3][4];
#pragma unroll
    for (int ni = 0; ni < 3; ni++)
#pragma unroll
        for (int mi = 0; mi < 4; mi++) acc[ni][mi] = f32x4{0.f, 0.f, 0.f, 0.f};
#pragma unroll
    for (int kk = 0; kk < 3; kk++)
#pragma unroll
        for (int ni = 0; ni < 3; ni++)
#pragma unroll
            for (int mi = 0; mi < 4; mi++)
                acc[ni][mi] = __builtin_amdgcn_mfma_f32_16x16x32_bf16(
                    af[ni][kk], bf[mi][kk], acc[ni][mi], 0, 0, 0);

#pragma unroll
    for (int ni = 0; ni < 3; ni++) {
        int colb = n0 + nh * 48 + ni * 16 + quad * 4;
        float4 bv = *(const float4*)&bias[colb];
#pragma unroll
        for (int mi = 0; mi < 4; mi++) {
            size_t row = m0 + mh * 64 + mi * 16 + l16;
            float v0 = acc[ni][mi][0] + bv.x, v1 = acc[ni][mi][1] + bv.y;
            float v2 = acc[ni][mi][2] + bv.z, v3 = acc[ni][mi][3] + bv.w;
            if (EPI == 1) {
                v0 = 0.5f * v0 * (1.f + erff(v0 * 0.70710678118654752f));
                v1 = 0.5f * v1 * (1.f + erff(v1 * 0.70710678118654752f));
                v2 = 0.5f * v2 * (1.f + erff(v2 * 0.70710678118654752f));
                v3 = 0.5f * v3 * (1.f + erff(v3 * 0.70710678118654752f));
            }
            unsigned int d0 = ((unsigned int)f2bf(v1) << 16) | f2bf(v0);
            unsigned int d1 = ((unsigned int)f2bf(v3) << 16) | f2bf(v2);
            *(uint2*)&Cout[row * N + colb] = make_uint2(d0, d1);
        }
    }
}

// ---------------------------------------------------------------------------
// LDS-free GEMM + bias + residual -> T f32 + fused epilogue -> Yh bf16:
// LNM=1: LayerNorm(g,bt); LNM=0: plain cast. K in {96,384}.
// ---------------------------------------------------------------------------
template <int LNM>
__global__ __launch_bounds__(256) void gemm_res(const u16* __restrict__ Xh,
        const u16* __restrict__ W, const float* __restrict__ bias,
        const float* __restrict__ res, float* __restrict__ Tout,
        const float* __restrict__ g, const float* __restrict__ bt,
        u16* __restrict__ Yh, int K) {
    __shared__ float2 parts[256];
    int tid = threadIdx.x;
    int w = tid >> 6, lane = tid & 63, quad = lane >> 4, l16 = lane & 15;
    int mh = w & 1, nh = w >> 1;
    size_t m0 = (size_t)blockIdx.x * 128;

    f32x4 acc[3][4];
#pragma unroll
    for (int ni = 0; ni < 3; ni++)
#pragma unroll
        for (int mi = 0; mi < 4; mi++) acc[ni][mi] = f32x4{0.f, 0.f, 0.f, 0.f};

    for (int k0 = 0; k0 < K; k0 += 96) {
        bf16x8 af[3][3], bf[4][3];
#pragma unroll
        for (int ni = 0; ni < 3; ni++)
#pragma unroll
            for (int kk = 0; kk < 3; kk++)
                af[ni][kk] = *(const bf16x8*)&W[(size_t)(nh * 48 + ni * 16 + l16) * K + k0 + kk * 32 + quad * 8];
#pragma unroll
        for (int mi = 0; mi < 4; mi++)
#pragma unroll
            for (int kk = 0; kk < 3; kk++)
                bf[mi][kk] = *(const bf16x8*)&Xh[(m0 + mh * 64 + mi * 16 + l16) * K + k0 + kk * 32 + quad * 8];
#pragma unroll
        for (int kk = 0; kk < 3; kk++)
#pragma unroll
            for (int ni = 0; ni < 3; ni++)
#pragma unroll
                for (int mi = 0; mi < 4; mi++)
                    acc[ni][mi] = __builtin_amdgcn_mfma_f32_16x16x32_bf16(
                        af[ni][kk], bf[mi][kk], acc[ni][mi], 0, 0, 0);
    }

#pragma unroll
    for (int ni = 0; ni < 3; ni++) {
        int colb = nh * 48 + ni * 16 + quad * 4;
        float4 bv = *(const float4*)&bias[colb];
#pragma unroll
        for (int mi = 0; mi < 4; mi++) {
            size_t row = m0 + mh * 64 + mi * 16 + l16;
            float4 rv = *(const float4*)&res[row * 96 + colb];
            acc[ni][mi][0] += bv.x + rv.x;
            acc[ni][mi][1] += bv.y + rv.y;
            acc[ni][mi][2] += bv.z + rv.z;
            acc[ni][mi][3] += bv.w + rv.w;
            *(f32x4*)&Tout[row * 96 + colb] = acc[ni][mi];
        }
    }

    if (LNM == 1) {
        float sm4[4], qm4[4];
#pragma unroll
        for (int mi = 0; mi < 4; mi++) {
            float s = 0.f, q = 0.f;
#pragma unroll
            for (int ni = 0; ni < 3; ni++)
#pragma unroll
                for (int r = 0; r < 4; r++) {
                    float v = acc[ni][mi][r];
                    s += v; q += v * v;
                }
            s += __shfl_xor(s, 16, 64); s += __shfl_xor(s, 32, 64);
            q += __shfl_xor(q, 16, 64); q += __shfl_xor(q, 32, 64);
            sm4[mi] = s; qm4[mi] = q;
        }
        __syncthreads();
        if (quad == 0) {
#pragma unroll
            for (int mi = 0; mi < 4; mi++)
                parts[(mh * 64 + mi * 16 + l16) * 2 + nh] = make_float2(sm4[mi], qm4[mi]);
        }
        __syncthreads();
        float mean4[4], rstd4[4];
#pragma unroll
        for (int mi = 0; mi < 4; mi++) {
            float2 oth = parts[(mh * 64 + mi * 16 + l16) * 2 + (nh ^ 1)];
            float ts_ = sm4[mi] + oth.x, tq = qm4[mi] + oth.y;
            float mean = ts_ * (1.f / 96.f);
            float var = tq * (1.f / 96.f) - mean * mean;
            mean4[mi] = mean;
            rstd4[mi] = rsqrtf(var + 1e-5f);
        }
#pragma unroll
        for (int ni = 0; ni < 3; ni++) {
            int colb = nh * 48 + ni * 16 + quad * 4;
            float4 g4 = *(const float4*)&g[colb];
            float4 b4 = *(const float4*)&bt[colb];
#pragma unroll
            for (int mi = 0; mi < 4; mi++) {
                size_t row = m0 + mh * 64 + mi * 16 + l16;
                float y0 = (acc[ni][mi][0] - mean4[mi]) * rstd4[mi] * g4.x + b4.x;
                float y1 = (acc[ni][mi][1] - mean4[mi]) * rstd4[mi] * g4.y + b4.y;
                float y2 = (acc[ni][mi][2] - mean4[mi]) * rstd4[mi] * g4.z + b4.z;
                float y3 = (acc[ni][mi][3] - mean4[mi]) * rstd4[mi] * g4.w + b4.w;
                unsigned int d0 = ((unsigned int)f2bf(y1) << 16) | f2bf(y0);
                unsigned int d1 = ((unsigned int)f2bf(y3) << 16) | f2bf(y2);
                *(uint2*)&Yh[row * 96 + colb] = make_uint2(d0, d1);
            }
        }
    } else {
#pragma unroll
        for (int ni = 0; ni < 3; ni++) {
            int colb = nh * 48 + ni * 16 + quad * 4;
#pragma unroll
            for (int mi = 0; mi < 4; mi++) {
                size_t row = m0 + mh * 64 + mi * 16 + l16;
                unsigned int d0 = ((unsigned int)f2bf(acc[ni][mi][1]) << 16) | f2bf(acc[ni][mi][0]);
                unsigned int d1 = ((unsigned int)f2bf(acc[ni][mi][3]) << 16) | f2bf(acc[ni][mi][2]);
                *(uint2*)&Yh[row * 96 + colb] = make_uint2(d0, d1);
            }
        }
    }
}

// ---------------------------------------------------------------------------
// MFMA window attention v2 (unchanged from passing R4-R7).
// ---------------------------------------------------------------------------
__global__ __launch_bounds__(192, 3) void attn_mfma(const u16* __restrict__ qkv,
        const float* __restrict__ BT, u16* __restrict__ ao, int shift) {
    __shared__ u16 Pl[3][64 * 72];
    __shared__ u16 vts[3][16 * 72];

    int tid = threadIdx.x;
    int w = tid >> 6, lane = tid & 63, quad = lane >> 4, l16 = lane & 15;
    int Wd = blockIdx.x;
    int bb = Wd >> 8, wl = Wd & 255, wh = wl >> 4, ww = wl & 15;
    int type = ((wh == 15) ? 2 : 0) + ((ww == 15) ? 1 : 0);

    int toks4[4], tokV;
#pragma unroll
    for (int t = 0; t < 4; t++) {
        int a = t * 16 + l16; if (a > 48) a = 48;
        int r = (a * 37) >> 8, c = a - r * 7;
        int h = wh * 7 + r, wq = ww * 7 + c;
        if (shift) { h += 3; if (h >= 112) h -= 112; wq += 3; if (wq >= 112) wq -= 112; }
        toks4[t] = bb * 12544 + h * 112 + wq;
    }
    {
        int a = lane > 48 ? 48 : lane;
        int r = (a * 37) >> 8, c = a - r * 7;
        int h = wh * 7 + r, wq = ww * 7 + c;
        if (shift) { h += 3; if (h >= 112) h -= 112; wq += 3; if (wq >= 112) wq -= 112; }
        tokV = bb * 12544 + h * 112 + wq;
    }

    u16* Pw = Pl[w];
    u16* vw = vts[w];

    for (int i = lane; i < 240; i += 64) {
        int rrow = i / 15, key = 49 + (i - rrow * 15);
        vw[rrow * 72 + key] = 0;
    }

    for (int hh = 0; hh < 2; hh++) {
        int head = w * 2 + hh;

        union { u32x4 u; bf16x8 h; } qf[4], kf[4];
#pragma unroll
        for (int t = 0; t < 4; t++) {
            u32x4 zq = {0u, 0u, 0u, 0u}, zk = {0u, 0u, 0u, 0u};
            if (quad < 2) {
                const u16* rb = qkv + (size_t)toks4[t] * 288 + head * 16 + quad * 8;
                zq = *(const u32x4*)(rb);
                zk = *(const u32x4*)(rb + 96);
            }
            qf[t].u = zq; kf[t].u = zk;
        }

        if (lane < 49) {
            const u16* vb = qkv + (size_t)tokV * 288 + head * 16 + 192;
            union { u32x4 v; unsigned int u[4]; } v0, v1;
            v0.v = *(const u32x4*)(vb);
            v1.v = *(const u32x4*)(vb + 8);
#pragma unroll
            for (int j = 0; j < 4; j++) {
                vw[(2 * j) * 72 + lane]         = (u16)(v0.u[j] & 0xffffu);
                vw[(2 * j + 1) * 72 + lane]     = (u16)(v0.u[j] >> 16);
                vw[(8 + 2 * j) * 72 + lane]     = (u16)(v1.u[j] & 0xffffu);
                vw[(8 + 2 * j + 1) * 72 + lane] = (u16)(v1.u[j] >> 16);
            }
        }

        f32x4 S[4][4];
#pragma unroll
        for (int kt = 0; kt < 4; kt++)
#pragma unroll
            for (int qt = 0; qt < 4; qt++)
                S[kt][qt] = __builtin_amdgcn_mfma_f32_16x16x32_bf16(
                    kf[kt].h, qf[qt].h, f32x4{0.f, 0.f, 0.f, 0.f}, 0, 0, 0);

        const float* bbase = BT + (size_t)(type * 6 + head) * 4096;
        float rinv[4];
#pragma unroll
        for (int qt = 0; qt < 4; qt++) {
            f32x4 bv[4];
#pragma unroll
            for (int kt = 0; kt < 4; kt++)
                bv[kt] = *(const f32x4*)&bbase[(size_t)(qt * 16 + l16) * 64 + kt * 16 + quad * 4];
            float mx = -3e38f;
#pragma unroll
            for (int kt = 0; kt < 4; kt++)
#pragma unroll
                for (int r = 0; r < 4; r++) {
                    float v = fmaf(S[kt][qt][r], 0.25f, bv[kt][r]);
                    S[kt][qt][r] = v;
                    mx = fmaxf(mx, v);
                }
            mx = fmaxf(mx, __shfl_xor(mx, 16, 64));
            mx = fmaxf(mx, __shfl_xor(mx, 32, 64));
            float sm = 0.f;
#pragma unroll
            for (int kt = 0; kt < 4; kt++)
#pragma unroll
                for (int r = 0; r < 4; r++) {
                    float e = __expf(S[kt][qt][r] - mx);
                    S[kt][qt][r] = e;
                    sm += e;
                }
            sm += __shfl_xor(sm, 16, 64);
            sm += __shfl_xor(sm, 32, 64);
            rinv[qt] = 1.0f / sm;
        }

#pragma unroll
        for (int qt = 0; qt < 4; qt++)
#pragma unroll
            for (int kt = 0; kt < 4; kt++) {
                unsigned int d0 = ((unsigned int)f2bf(S[kt][qt][1]) << 16) | f2bf(S[kt][qt][0]);
                unsigned int d1 = ((unsigned int)f2bf(S[kt][qt][3]) << 16) | f2bf(S[kt][qt][2]);
                *(uint2*)&Pw[(qt * 16 + l16) * 72 + kt * 16 + quad * 4] = make_uint2(d0, d1);
            }

        bf16x8 vf[2];
#pragma unroll
        for (int ksp = 0; ksp < 2; ksp++)
            vf[ksp] = *(const bf16x8*)&vw[l16 * 72 + ksp * 32 + quad * 8];
#pragma unroll
        for (int qt = 0; qt < 4; qt++) {
            f32x4 O = {0.f, 0.f, 0.f, 0.f};
#pragma unroll
            for (int ksp = 0; ksp < 2; ksp++) {
                bf16x8 pf = *(const bf16x8*)&Pw[(qt * 16 + l16) * 72 + ksp * 32 + quad * 8];
                O = __builtin_amdgcn_mfma_f32_16x16x32_bf16(vf[ksp], pf, O, 0, 0, 0);
            }
            int a = qt * 16 + l16;
            if (a < 49) {
                float ri = rinv[qt];
                unsigned int d0 = ((unsigned int)f2bf(O[1] * ri) << 16) | f2bf(O[0] * ri);
                unsigned int d1 = ((unsigned int)f2bf(O[3] * ri) << 16) | f2bf(O[2] * ri);
                *(uint2*)&ao[(size_t)toks4[qt] * 96 + head * 16 + quad * 4] = make_uint2(d0, d1);
            }
        }
    }
}

// ---------------------------------------------------------------------------
// Final 1x1 conv (96->48) + ReLU via MFMA, LDS-free direct fragments.
// ---------------------------------------------------------------------------
__global__ __launch_bounds__(256) void outconv_mfma(const u16* __restrict__ Th,
        const u16* __restrict__ Woc, const float* __restrict__ ob,
        float* __restrict__ out) {
    int tid = threadIdx.x;
    int w = tid >> 6, lane = tid & 63, quad = lane >> 4, l16 = lane & 15;
    int t0 = blockIdx.x * 128, b = blockIdx.y;
    size_t m0 = (size_t)b * 12544 + t0;

    bf16x8 af[2][3], bfr[3][3];
#pragma unroll
    for (int mi = 0; mi < 2; mi++)
#pragma unroll
        for (int kk = 0; kk < 3; kk++)
            af[mi][kk] = *(const bf16x8*)&Th[(m0 + w * 32 + mi * 16 + l16) * 96 + kk * 32 + quad * 8];
#pragma unroll
    for (int ni = 0; ni < 3; ni++)
#pragma unroll
        for (int kk = 0; kk < 3; kk++)
            bfr[ni][kk] = *(const bf16x8*)&Woc[(size_t)(ni * 16 + l16) * 96 + kk * 32 + quad * 8];

    f32x4 acc[2][3];
#pragma unroll
    for (int mi = 0; mi < 2; mi++)
#pragma unroll
        for (int ni = 0; ni < 3; ni++) acc[mi][ni] = f32x4{0.f, 0.f, 0.f, 0.f};
#pragma unroll
    for (int kk = 0; kk < 3; kk++)
#pragma unroll
        for (int mi = 0; mi < 2; mi++)
#pragma unroll
            for (int ni = 0; ni < 3; ni++)
                acc[mi][ni] = __builtin_amdgcn_mfma_f32_16x16x32_bf16(
                    af[mi][kk], bfr[ni][kk], acc[mi][ni], 0, 0, 0);

#pragma unroll
    for (int mi = 0; mi < 2; mi++)
#pragma unroll
        for (int ni = 0; ni < 3; ni++) {
            int co = ni * 16 + l16;
            float bb = ob[co];
            f32x4 o = {fmaxf(acc[mi][ni][0] + bb, 0.f), fmaxf(acc[mi][ni][1] + bb, 0.f),
                       fmaxf(acc[mi][ni][2] + bb, 0.f), fmaxf(acc[mi][ni][3] + bb, 0.f)};
            *(f32x4*)&out[((size_t)b * 48 + co) * 12544 + t0 + w * 32 + mi * 16 + quad * 4] = o;
        }
}

// ---------------------------------------------------------------------------
extern "C" void kernel_launch(void* const* d_in, const int* in_sizes, int n_in,
                              void* d_out, int out_size, void* d_ws, size_t ws_size,
                              hipStream_t stream) {
    const float* x     = (const float*)d_in[0];
    const float* up_w  = (const float*)d_in[1];
    const float* up_b  = (const float*)d_in[2];
    const float* bn_g  = (const float*)d_in[3];
    const float* bn_b  = (const float*)d_in[4];
    const float* bn_m  = (const float*)d_in[5];
    const float* bn_v  = (const float*)d_in[6];
    const float* n1g   = (const float*)d_in[7];
    const float* n1b   = (const float*)d_in[8];
    const float* qkvw  = (const float*)d_in[9];
    const float* qkvb  = (const float*)d_in[10];
    const float* projw = (const float*)d_in[11];
    const float* projb = (const float*)d_in[12];
    const float* rel   = (const float*)d_in[13];
    const float* n2g   = (const float*)d_in[14];
    const float* n2b   = (const float*)d_in[15];
    const float* f1w   = (const float*)d_in[16];
    const float* f1b   = (const float*)d_in[17];
    const float* f2w   = (const float*)d_in[18];
    const float* f2b   = (const float*)d_in[19];
    const float* outw  = (const float*)d_in[20];
    const float* outb  = (const float*)d_in[21];
    float* out = (float*)d_out;

    char* base = (char*)d_ws;
    float* T  = (float*)base;                       base += (size_t)M_TOK * 96 * 4;
    u16* XBh  = (u16*)base;                         base += (size_t)M_TOK * 96 * 2;
    u16* BIGh = (u16*)base;                         base += (size_t)M_TOK * 384 * 2;
    u16* xT   = (u16*)base;                         base += (size_t)8 * 3136 * 192 * 2;
    u16* Wc   = (u16*)base;                         base += (size_t)16 * 96 * 192 * 2;
    u16* Wh   = (u16*)base;                         base += (size_t)225792 * 2;
    float* BT = (float*)base;
    u16* qkvwh = Wh;
    u16* projwh = Wh + 55296;
    u16* f1wh = Wh + 73728;
    u16* f2wh = Wh + 147456;
    u16* outwh = Wh + 221184;

    prep_kernel<<<1218, 256, 0, stream>>>(qkvw, projw, f1w, f2w, outw, up_w, rel, Wh, Wc, BT);
    transpose_kernel<<<dim3(49, 8), 256, 0, stream>>>(x, xT);
    conv_mfma<<<dim3(49, 4, 8), 256, 0, stream>>>(xT, Wc, up_b, bn_g, bn_b, bn_m, bn_v,
                                                  n1g, n1b, T, XBh);

    for (int blk = 0; blk < 2; blk++) {
        int shift = (blk == 0) ? 0 : 3;
        gemm_act<0><<<dim3(3, M_TOK / 128), 256, 0, stream>>>(
            XBh, qkvwh + blk * 27648, qkvb + blk * 288, BIGh, 288);
        attn_mfma<<<2048, 192, 0, stream>>>(BIGh, BT + (size_t)blk * 98304, XBh, shift);
        gemm_res<1><<<M_TOK / 128, 256, 0, stream>>>(
            XBh, projwh + blk * 9216, projb + blk * 96, T, T,
            n2g + blk * 96, n2b + blk * 96, XBh, 96);
        gemm_act<1><<<dim3(4, M_TOK / 128), 256, 0, stream>>>(
            XBh, f1wh + blk * 36864, f1b + blk * 384, BIGh, 384);
        if (blk == 0) {
            gemm_res<1><<<M_TOK / 128, 256, 0, stream>>>(
                BIGh, f2wh + blk * 36864, f2b + blk * 96, T, T,
                n1g + 96, n1b + 96, XBh, 384);
        } else {
            gemm_res<0><<<M_TOK / 128, 256, 0, stream>>>(
                BIGh, f2wh + blk * 36864, f2b + blk * 96, T, T,
                nullptr, nullptr, XBh, 384);
        }
    }

    outconv_mfma<<<dim3(98, 8), 256, 0, stream>>>(XBh, outwh, outb, out);
}

// Round 9
// 592.332 us; speedup vs baseline: 1.0196x; 1.0196x over previous
//
#include <hip/hip_runtime.h>
#include <math.h>

#define M_TOK 100352   // 8*112*112 tokens
#define NHEAD 6

typedef unsigned short u16;
typedef __attribute__((ext_vector_type(8))) short bf16x8;
typedef __attribute__((ext_vector_type(4))) float f32x4;
typedef __attribute__((ext_vector_type(4))) unsigned int u32x4;

__device__ inline u16 f2bf(float f) {
    union { float f; unsigned int i; } v; v.f = f;
    unsigned int r = v.i + 0x7fffu + ((v.i >> 16) & 1u);
    return (u16)(r >> 16);
}

// ---------------------------------------------------------------------------
// Merged prep: [0,882) cast weights; [882,1170) fold conv w; [1170,1218) bias.
// ---------------------------------------------------------------------------
__global__ __launch_bounds__(256) void prep_kernel(const float* __restrict__ qkvw,
        const float* __restrict__ projw, const float* __restrict__ f1w,
        const float* __restrict__ f2w, const float* __restrict__ outw,
        const float* __restrict__ up_w, const float* __restrict__ rel,
        u16* __restrict__ Wh, u16* __restrict__ Wc, float* __restrict__ BT) {
    int bid = blockIdx.x;
    if (bid < 882) {
        int i = bid * 256 + threadIdx.x;
        if (i < 55296) Wh[i] = f2bf(qkvw[i]);
        else if (i < 73728) Wh[i] = f2bf(projw[i - 55296]);
        else if (i < 147456) Wh[i] = f2bf(f1w[i - 73728]);
        else if (i < 221184) Wh[i] = f2bf(f2w[i - 147456]);
        else if (i < 225792) Wh[i] = f2bf(outw[i - 221184]);
        return;
    }
    if (bid < 1170) {
        int idx = (bid - 882) * 256 + threadIdx.x;
        if (idx >= 96 * 4 * 192) return;
        int c2 = idx / 768;
        int rem = idx - c2 * 768;
        int p = rem / 192;
        int ci = rem - p * 192;
        int po = p >> 1, pw = p & 1;
        const float* w = up_w + (c2 * 192 + ci) * 9;
        float w9[9];
#pragma unroll
        for (int k = 0; k < 9; k++) w9[k] = w[k];
        float r0[3], r1[3];
#pragma unroll
        for (int kw = 0; kw < 3; kw++) {
            if (po == 0) { r0[kw] = w9[kw];              r1[kw] = w9[3 + kw] + w9[6 + kw]; }
            else         { r0[kw] = w9[kw] + w9[3 + kw]; r1[kw] = w9[6 + kw]; }
        }
        float o00, o01, o10, o11;
        if (pw == 0) { o00 = r0[0];         o01 = r0[1] + r0[2]; o10 = r1[0];         o11 = r1[1] + r1[2]; }
        else         { o00 = r0[0] + r0[1]; o01 = r0[2];         o10 = r1[0] + r1[1]; o11 = r1[2]; }
        size_t base = ((size_t)p * 4 * 96 + c2) * 192 + ci;
        Wc[base + 0 * 96 * 192] = f2bf(o00);
        Wc[base + 1 * 96 * 192] = f2bf(o01);
        Wc[base + 2 * 96 * 192] = f2bf(o10);
        Wc[base + 3 * 96 * 192] = f2bf(o11);
        return;
    }
    {
        int blkid = bid - 1170;                // blk*24 + type*6 + head
        int blk = blkid / 24;
        int rem = blkid - blk * 24;
        int type = rem / 6, head = rem - (rem / 6) * 6;
        const float* relp = rel + blk * 1014;
        bool shift = (blk == 1);
        for (int i = threadIdx.x; i < 4096; i += 256) {
            int a = i >> 6, k = i & 63;
            float v;
            if (k >= 49) v = -1e30f;
            else if (a >= 49) v = 0.f;
            else {
                int ah = (a * 37) >> 8, aw = a - ah * 7;
                int kh = (k * 37) >> 8, kw = k - kh * 7;
                v = relp[((ah - kh + 6) * 13 + (aw - kw + 6)) * 6 + head];
                if (shift) {
                    int lha = (type & 2) ? (ah < 4 ? 1 : 2) : 0;
                    int lwa = (type & 1) ? (aw < 4 ? 1 : 2) : 0;
                    int lhk = (type & 2) ? (kh < 4 ? 1 : 2) : 0;
                    int lwk = (type & 1) ? (kw < 4 ? 1 : 2) : 0;
                    if (lha != lhk || lwa != lwk) v -= 100.f;
                }
            }
            BT[(size_t)blkid * 4096 + i] = v;
        }
    }
}

// ---------------------------------------------------------------------------
// x [b][192][56][56] f32 -> xT [b][3136][192] bf16 (XOR-swizzled LDS).
// ---------------------------------------------------------------------------
__global__ __launch_bounds__(256) void transpose_kernel(const float* __restrict__ x,
                                                        u16* __restrict__ xT) {
    __shared__ unsigned int ts[64 * 96];
    int b = blockIdx.y;
    int pix0 = blockIdx.x * 64;
    int tid = threadIdx.x;
    int p = tid & 63, dg = tid >> 6;
    const float* xb = x + (size_t)b * 192 * 3136 + pix0 + p;
    for (int d = dg; d < 96; d += 4) {
        float v0 = xb[(size_t)(2 * d) * 3136];
        float v1 = xb[(size_t)(2 * d + 1) * 3136];
        unsigned int pk = ((unsigned int)f2bf(v1) << 16) | (unsigned int)f2bf(v0);
        ts[p * 96 + ((d & ~31) | ((d & 31) ^ (p & 31)))] = pk;
    }
    __syncthreads();
    for (int i = tid; i < 1536; i += 256) {
        int pp = i / 24, c = i - pp * 24;
        unsigned int r[4];
#pragma unroll
        for (int j = 0; j < 4; j++) {
            int d = c * 4 + j;
            r[j] = ts[pp * 96 + ((d & ~31) | ((d & 31) ^ (pp & 31)))];
        }
        u32x4 v = {r[0], r[1], r[2], r[3]};
        *(u32x4*)&xT[((size_t)b * 3136 + pix0 + pp) * 192 + c * 8] = v;
    }
}

// ---------------------------------------------------------------------------
// Implicit-GEMM conv via MFMA: xs staged once; W fragments direct from global
// with REGISTER DOUBLE-BUFFER at tap granularity (software pipeline — R8's
// direct loads exposed L2 latency; this hides it within-wave).
// BN + ReLU -> T f32 + fused LN1 -> XBh bf16.
// ---------------------------------------------------------------------------
__global__ __launch_bounds__(256, 2) void conv_mfma(const u16* __restrict__ xT,
        const u16* __restrict__ Wc, const float* __restrict__ up_b,
        const float* __restrict__ bn_g, const float* __restrict__ bn_b,
        const float* __restrict__ bn_m, const float* __restrict__ bn_v,
        const float* __restrict__ lg, const float* __restrict__ lb,
        float* __restrict__ T, u16* __restrict__ XBh) {
    __shared__ u16 xs[81 * 200];
    __shared__ float2 parts[128];
    int tile = blockIdx.x, p = blockIdx.y, b = blockIdx.z;
    int po = p >> 1, pw = p & 1;
    int a0 = (tile / 7) * 8, b0 = (tile % 7) * 8;
    int rro = a0 - 1 + po, cco = b0 - 1 + pw;
    int tid = threadIdx.x;
    int w = tid >> 6, lane = tid & 63, quad = lane >> 4, l16 = lane & 15;
    int mbase = (w & 1) * 32;
    int nt0 = (w >> 1) * 3;
    int half = w >> 1;

    // W row bases for this wave's 3 n-tiles (parity p); frag k-offset = ks*32
    const u16* wrow[3];
#pragma unroll
    for (int ni = 0; ni < 3; ni++)
        wrow[ni] = Wc + ((size_t)p * 4 * 96 + (nt0 + ni) * 16 + l16) * 192 + quad * 8;

    // prefetch tap 0 weights (overlaps xs staging below)
    bf16x8 Wb[2][3][6];
#pragma unroll
    for (int ni = 0; ni < 3; ni++)
#pragma unroll
        for (int ks = 0; ks < 6; ks++)
            Wb[0][ni][ks] = *(const bf16x8*)(wrow[ni] + ks * 32);

    for (int i = tid; i < 1944; i += 256) {
        int pix = i / 24, c = i - pix * 24;
        int rr = pix / 9, cc = pix - rr * 9;
        int gr = rro + rr, gc = cco + cc;
        u32x4 v = {0u, 0u, 0u, 0u};
        if ((unsigned)gr < 56u && (unsigned)gc < 56u)
            v = *(const u32x4*)&xT[((size_t)b * 3136 + gr * 56 + gc) * 192 + c * 8];
        *(u32x4*)&xs[pix * 200 + c * 8] = v;
    }

    f32x4 acc[2][3];
#pragma unroll
    for (int mi = 0; mi < 2; mi++)
#pragma unroll
        for (int ni = 0; ni < 3; ni++) acc[mi][ni] = f32x4{0.f, 0.f, 0.f, 0.f};

    int aoffp[2];
#pragma unroll
    for (int mi = 0; mi < 2; mi++) {
        int pixel = mbase + mi * 16 + l16;
        aoffp[mi] = ((pixel >> 3) * 9 + (pixel & 7)) * 200;
    }

    __syncthreads();

#pragma unroll
    for (int tap = 0; tap < 4; tap++) {
        int cur = tap & 1, nxt = cur ^ 1;
        if (tap < 3) {   // prefetch next tap's W while computing this tap
            size_t woff = (size_t)(tap + 1) * 96 * 192;
#pragma unroll
            for (int ni = 0; ni < 3; ni++)
#pragma unroll
                for (int ks = 0; ks < 6; ks++)
                    Wb[nxt][ni][ks] = *(const bf16x8*)(wrow[ni] + woff + ks * 32);
        }
        int tsh = ((tap >> 1) * 9 + (tap & 1)) * 200;
#pragma unroll
        for (int ks = 0; ks < 6; ks++) {
            bf16x8 af[2];
#pragma unroll
            for (int mi = 0; mi < 2; mi++)
                af[mi] = *(const bf16x8*)&xs[aoffp[mi] + tsh + ks * 32 + quad * 8];
#pragma unroll
            for (int mi = 0; mi < 2; mi++)
#pragma unroll
                for (int ni = 0; ni < 3; ni++)
                    acc[mi][ni] = __builtin_amdgcn_mfma_f32_16x16x32_bf16(
                        af[mi], Wb[cur][ni][ks], acc[mi][ni], 0, 0, 0);
        }
    }

    // BN + ReLU -> T (keep values in acc for LN)
#pragma unroll
    for (int ni = 0; ni < 3; ni++) {
        int c2 = (nt0 + ni) * 16 + l16;
        float sc = bn_g[c2] * rsqrtf(bn_v[c2] + 1e-5f);
        float sh = (up_b[c2] - bn_m[c2]) * sc + bn_b[c2];
#pragma unroll
        for (int mi = 0; mi < 2; mi++) {
#pragma unroll
            for (int reg = 0; reg < 4; reg++) {
                int pixel = mbase + mi * 16 + quad * 4 + reg;
                int pr = pixel >> 3, pc = pixel & 7;
                int oh = 2 * (a0 + pr) + po, ow = 2 * (b0 + pc) + pw;
                size_t tok = (size_t)b * 12544 + oh * 112 + ow;
                float v = fmaxf(acc[mi][ni][reg] * sc + sh, 0.f);
                acc[mi][ni][reg] = v;
                T[tok * 96 + c2] = v;
            }
        }
    }

    // fused LN over channels
    float sA[2][4], qA[2][4];
#pragma unroll
    for (int mi = 0; mi < 2; mi++)
#pragma unroll
        for (int reg = 0; reg < 4; reg++) {
            float s = acc[mi][0][reg] + acc[mi][1][reg] + acc[mi][2][reg];
            float q = acc[mi][0][reg] * acc[mi][0][reg] + acc[mi][1][reg] * acc[mi][1][reg]
                    + acc[mi][2][reg] * acc[mi][2][reg];
#pragma unroll
            for (int d = 1; d < 16; d <<= 1) {
                s += __shfl_xor(s, d, 64);
                q += __shfl_xor(q, d, 64);
            }
            sA[mi][reg] = s; qA[mi][reg] = q;
        }
    if (l16 == 0) {
#pragma unroll
        for (int mi = 0; mi < 2; mi++)
#pragma unroll
            for (int reg = 0; reg < 4; reg++) {
                int pixel = mbase + mi * 16 + quad * 4 + reg;
                parts[pixel * 2 + half] = make_float2(sA[mi][reg], qA[mi][reg]);
            }
    }
    __syncthreads();
    float gcl[3], bcl[3];
#pragma unroll
    for (int ni = 0; ni < 3; ni++) {
        int c2 = (nt0 + ni) * 16 + l16;
        gcl[ni] = lg[c2]; bcl[ni] = lb[c2];
    }
#pragma unroll
    for (int mi = 0; mi < 2; mi++)
#pragma unroll
        for (int reg = 0; reg < 4; reg++) {
            int pixel = mbase + mi * 16 + quad * 4 + reg;
            float2 oth = parts[pixel * 2 + (half ^ 1)];
            float ts_ = sA[mi][reg] + oth.x, tq = qA[mi][reg] + oth.y;
            float mean = ts_ * (1.f / 96.f);
            float var = tq * (1.f / 96.f) - mean * mean;
            float rstd = rsqrtf(var + 1e-5f);
            int pr = pixel >> 3, pc = pixel & 7;
            int oh = 2 * (a0 + pr) + po, ow = 2 * (b0 + pc) + pw;
            size_t tok = (size_t)b * 12544 + oh * 112 + ow;
#pragma unroll
            for (int ni = 0; ni < 3; ni++) {
                int c2 = (nt0 + ni) * 16 + l16;
                XBh[tok * 96 + c2] = f2bf((acc[mi][ni][reg] - mean) * rstd * gcl[ni] + bcl[ni]);
            }
        }
}

// ---------------------------------------------------------------------------
// LDS-free bf16 GEMM (K=96): C = Xh @ W^T + bias [,GELU] -> bf16.
// ---------------------------------------------------------------------------
template <int EPI>
__global__ __launch_bounds__(256) void gemm_act(const u16* __restrict__ Xh,
        const u16* __restrict__ W, const float* __restrict__ bias,
        u16* __restrict__ Cout, int N) {
    int tid = threadIdx.x;
    int w = tid >> 6, lane = tid & 63, quad = lane >> 4, l16 = lane & 15;
    int mh = w & 1, nh = w >> 1;
    int n0 = blockIdx.x * 96;
    size_t m0 = (size_t)blockIdx.y * 128;

    bf16x8 af[3][3], bf[4][3];
#pragma unroll
    for (int ni = 0; ni < 3; ni++)
#pragma unroll
        for (int kk = 0; kk < 3; kk++)
            af[ni][kk] = *(const bf16x8*)&W[(size_t)(n0 + nh * 48 + ni * 16 + l16) * 96 + kk * 32 + quad * 8];
#pragma unroll
    for (int mi = 0; mi < 4; mi++)
#pragma unroll
        for (int kk = 0; kk < 3; kk++)
            bf[mi][kk] = *(const bf16x8*)&Xh[(m0 + mh * 64 + mi * 16 + l16) * 96 + kk * 32 + quad * 8];

    f32x4 acc[3][4];
#pragma unroll
    for (int ni = 0; ni < 3; ni++)
#pragma unroll
        for (int mi = 0; mi < 4; mi++) acc[ni][mi] = f32x4{0.f, 0.f, 0.f, 0.f};
#pragma unroll
    for (int kk = 0; kk < 3; kk++)
#pragma unroll
        for (int ni = 0; ni < 3; ni++)
#pragma unroll
            for (int mi = 0; mi < 4; mi++)
                acc[ni][mi] = __builtin_amdgcn_mfma_f32_16x16x32_bf16(
                    af[ni][kk], bf[mi][kk], acc[ni][mi], 0, 0, 0);

#pragma unroll
    for (int ni = 0; ni < 3; ni++) {
        int colb = n0 + nh * 48 + ni * 16 + quad * 4;
        float4 bv = *(const float4*)&bias[colb];
#pragma unroll
        for (int mi = 0; mi < 4; mi++) {
            size_t row = m0 + mh * 64 + mi * 16 + l16;
            float v0 = acc[ni][mi][0] + bv.x, v1 = acc[ni][mi][1] + bv.y;
            float v2 = acc[ni][mi][2] + bv.z, v3 = acc[ni][mi][3] + bv.w;
            if (EPI == 1) {
                v0 = 0.5f * v0 * (1.f + erff(v0 * 0.70710678118654752f));
                v1 = 0.5f * v1 * (1.f + erff(v1 * 0.70710678118654752f));
                v2 = 0.5f * v2 * (1.f + erff(v2 * 0.70710678118654752f));
                v3 = 0.5f * v3 * (1.f + erff(v3 * 0.70710678118654752f));
            }
            unsigned int d0 = ((unsigned int)f2bf(v1) << 16) | f2bf(v0);
            unsigned int d1 = ((unsigned int)f2bf(v3) << 16) | f2bf(v2);
            *(uint2*)&Cout[row * N + colb] = make_uint2(d0, d1);
        }
    }
}

// ---------------------------------------------------------------------------
// LDS-free GEMM + bias + residual -> T f32 + fused epilogue -> Yh bf16.
// K now a template param: full unroll + launch_bounds(256,2) lets the
// scheduler hoist loads across k-steps (software pipelining).
// ---------------------------------------------------------------------------
template <int LNM, int K>
__global__ __launch_bounds__(256, 2) void gemm_res(const u16* __restrict__ Xh,
        const u16* __restrict__ W, const float* __restrict__ bias,
        const float* __restrict__ res, float* __restrict__ Tout,
        const float* __restrict__ g, const float* __restrict__ bt,
        u16* __restrict__ Yh) {
    __shared__ float2 parts[256];
    int tid = threadIdx.x;
    int w = tid >> 6, lane = tid & 63, quad = lane >> 4, l16 = lane & 15;
    int mh = w & 1, nh = w >> 1;
    size_t m0 = (size_t)blockIdx.x * 128;

    f32x4 acc[3][4];
#pragma unroll
    for (int ni = 0; ni < 3; ni++)
#pragma unroll
        for (int mi = 0; mi < 4; mi++) acc[ni][mi] = f32x4{0.f, 0.f, 0.f, 0.f};

#pragma unroll
    for (int k0 = 0; k0 < K; k0 += 96) {
        bf16x8 af[3][3], bf[4][3];
#pragma unroll
        for (int ni = 0; ni < 3; ni++)
#pragma unroll
            for (int kk = 0; kk < 3; kk++)
                af[ni][kk] = *(const bf16x8*)&W[(size_t)(nh * 48 + ni * 16 + l16) * K + k0 + kk * 32 + quad * 8];
#pragma unroll
        for (int mi = 0; mi < 4; mi++)
#pragma unroll
            for (int kk = 0; kk < 3; kk++)
                bf[mi][kk] = *(const bf16x8*)&Xh[(m0 + mh * 64 + mi * 16 + l16) * K + k0 + kk * 32 + quad * 8];
#pragma unroll
        for (int kk = 0; kk < 3; kk++)
#pragma unroll
            for (int ni = 0; ni < 3; ni++)
#pragma unroll
                for (int mi = 0; mi < 4; mi++)
                    acc[ni][mi] = __builtin_amdgcn_mfma_f32_16x16x32_bf16(
                        af[ni][kk], bf[mi][kk], acc[ni][mi], 0, 0, 0);
    }

#pragma unroll
    for (int ni = 0; ni < 3; ni++) {
        int colb = nh * 48 + ni * 16 + quad * 4;
        float4 bv = *(const float4*)&bias[colb];
#pragma unroll
        for (int mi = 0; mi < 4; mi++) {
            size_t row = m0 + mh * 64 + mi * 16 + l16;
            float4 rv = *(const float4*)&res[row * 96 + colb];
            acc[ni][mi][0] += bv.x + rv.x;
            acc[ni][mi][1] += bv.y + rv.y;
            acc[ni][mi][2] += bv.z + rv.z;
            acc[ni][mi][3] += bv.w + rv.w;
            *(f32x4*)&Tout[row * 96 + colb] = acc[ni][mi];
        }
    }

    if (LNM == 1) {
        float sm4[4], qm4[4];
#pragma unroll
        for (int mi = 0; mi < 4; mi++) {
            float s = 0.f, q = 0.f;
#pragma unroll
            for (int ni = 0; ni < 3; ni++)
#pragma unroll
                for (int r = 0; r < 4; r++) {
                    float v = acc[ni][mi][r];
                    s += v; q += v * v;
                }
            s += __shfl_xor(s, 16, 64); s += __shfl_xor(s, 32, 64);
            q += __shfl_xor(q, 16, 64); q += __shfl_xor(q, 32, 64);
            sm4[mi] = s; qm4[mi] = q;
        }
        __syncthreads();
        if (quad == 0) {
#pragma unroll
            for (int mi = 0; mi < 4; mi++)
                parts[(mh * 64 + mi * 16 + l16) * 2 + nh] = make_float2(sm4[mi], qm4[mi]);
        }
        __syncthreads();
        float mean4[4], rstd4[4];
#pragma unroll
        for (int mi = 0; mi < 4; mi++) {
            float2 oth = parts[(mh * 64 + mi * 16 + l16) * 2 + (nh ^ 1)];
            float ts_ = sm4[mi] + oth.x, tq = qm4[mi] + oth.y;
            float mean = ts_ * (1.f / 96.f);
            float var = tq * (1.f / 96.f) - mean * mean;
            mean4[mi] = mean;
            rstd4[mi] = rsqrtf(var + 1e-5f);
        }
#pragma unroll
        for (int ni = 0; ni < 3; ni++) {
            int colb = nh * 48 + ni * 16 + quad * 4;
            float4 g4 = *(const float4*)&g[colb];
            float4 b4 = *(const float4*)&bt[colb];
#pragma unroll
            for (int mi = 0; mi < 4; mi++) {
                size_t row = m0 + mh * 64 + mi * 16 + l16;
                float y0 = (acc[ni][mi][0] - mean4[mi]) * rstd4[mi] * g4.x + b4.x;
                float y1 = (acc[ni][mi][1] - mean4[mi]) * rstd4[mi] * g4.y + b4.y;
                float y2 = (acc[ni][mi][2] - mean4[mi]) * rstd4[mi] * g4.z + b4.z;
                float y3 = (acc[ni][mi][3] - mean4[mi]) * rstd4[mi] * g4.w + b4.w;
                unsigned int d0 = ((unsigned int)f2bf(y1) << 16) | f2bf(y0);
                unsigned int d1 = ((unsigned int)f2bf(y3) << 16) | f2bf(y2);
                *(uint2*)&Yh[row * 96 + colb] = make_uint2(d0, d1);
            }
        }
    } else {
#pragma unroll
        for (int ni = 0; ni < 3; ni++) {
            int colb = nh * 48 + ni * 16 + quad * 4;
#pragma unroll
            for (int mi = 0; mi < 4; mi++) {
                size_t row = m0 + mh * 64 + mi * 16 + l16;
                unsigned int d0 = ((unsigned int)f2bf(acc[ni][mi][1]) << 16) | f2bf(acc[ni][mi][0]);
                unsigned int d1 = ((unsigned int)f2bf(acc[ni][mi][3]) << 16) | f2bf(acc[ni][mi][2]);
                *(uint2*)&Yh[row * 96 + colb] = make_uint2(d0, d1);
            }
        }
    }
}

// ---------------------------------------------------------------------------
// MFMA window attention v2 (unchanged from passing R4-R8).
// ---------------------------------------------------------------------------
__global__ __launch_bounds__(192, 3) void attn_mfma(const u16* __restrict__ qkv,
        const float* __restrict__ BT, u16* __restrict__ ao, int shift) {
    __shared__ u16 Pl[3][64 * 72];
    __shared__ u16 vts[3][16 * 72];

    int tid = threadIdx.x;
    int w = tid >> 6, lane = tid & 63, quad = lane >> 4, l16 = lane & 15;
    int Wd = blockIdx.x;
    int bb = Wd >> 8, wl = Wd & 255, wh = wl >> 4, ww = wl & 15;
    int type = ((wh == 15) ? 2 : 0) + ((ww == 15) ? 1 : 0);

    int toks4[4], tokV;
#pragma unroll
    for (int t = 0; t < 4; t++) {
        int a = t * 16 + l16; if (a > 48) a = 48;
        int r = (a * 37) >> 8, c = a - r * 7;
        int h = wh * 7 + r, wq = ww * 7 + c;
        if (shift) { h += 3; if (h >= 112) h -= 112; wq += 3; if (wq >= 112) wq -= 112; }
        toks4[t] = bb * 12544 + h * 112 + wq;
    }
    {
        int a = lane > 48 ? 48 : lane;
        int r = (a * 37) >> 8, c = a - r * 7;
        int h = wh * 7 + r, wq = ww * 7 + c;
        if (shift) { h += 3; if (h >= 112) h -= 112; wq += 3; if (wq >= 112) wq -= 112; }
        tokV = bb * 12544 + h * 112 + wq;
    }

    u16* Pw = Pl[w];
    u16* vw = vts[w];

    for (int i = lane; i < 240; i += 64) {
        int rrow = i / 15, key = 49 + (i - rrow * 15);
        vw[rrow * 72 + key] = 0;
    }

    for (int hh = 0; hh < 2; hh++) {
        int head = w * 2 + hh;

        union { u32x4 u; bf16x8 h; } qf[4], kf[4];
#pragma unroll
        for (int t = 0; t < 4; t++) {
            u32x4 zq = {0u, 0u, 0u, 0u}, zk = {0u, 0u, 0u, 0u};
            if (quad < 2) {
                const u16* rb = qkv + (size_t)toks4[t] * 288 + head * 16 + quad * 8;
                zq = *(const u32x4*)(rb);
                zk = *(const u32x4*)(rb + 96);
            }
            qf[t].u = zq; kf[t].u = zk;
        }

        if (lane < 49) {
            const u16* vb = qkv + (size_t)tokV * 288 + head * 16 + 192;
            union { u32x4 v; unsigned int u[4]; } v0, v1;
            v0.v = *(const u32x4*)(vb);
            v1.v = *(const u32x4*)(vb + 8);
#pragma unroll
            for (int j = 0; j < 4; j++) {
                vw[(2 * j) * 72 + lane]         = (u16)(v0.u[j] & 0xffffu);
                vw[(2 * j + 1) * 72 + lane]     = (u16)(v0.u[j] >> 16);
                vw[(8 + 2 * j) * 72 + lane]     = (u16)(v1.u[j] & 0xffffu);
                vw[(8 + 2 * j + 1) * 72 + lane] = (u16)(v1.u[j] >> 16);
            }
        }

        f32x4 S[4][4];
#pragma unroll
        for (int kt = 0; kt < 4; kt++)
#pragma unroll
            for (int qt = 0; qt < 4; qt++)
                S[kt][qt] = __builtin_amdgcn_mfma_f32_16x16x32_bf16(
                    kf[kt].h, qf[qt].h, f32x4{0.f, 0.f, 0.f, 0.f}, 0, 0, 0);

        const float* bbase = BT + (size_t)(type * 6 + head) * 4096;
        float rinv[4];
#pragma unroll
        for (int qt = 0; qt < 4; qt++) {
            f32x4 bv[4];
#pragma unroll
            for (int kt = 0; kt < 4; kt++)
                bv[kt] = *(const f32x4*)&bbase[(size_t)(qt * 16 + l16) * 64 + kt * 16 + quad * 4];
            float mx = -3e38f;
#pragma unroll
            for (int kt = 0; kt < 4; kt++)
#pragma unroll
                for (int r = 0; r < 4; r++) {
                    float v = fmaf(S[kt][qt][r], 0.25f, bv[kt][r]);
                    S[kt][qt][r] = v;
                    mx = fmaxf(mx, v);
                }
            mx = fmaxf(mx, __shfl_xor(mx, 16, 64));
            mx = fmaxf(mx, __shfl_xor(mx, 32, 64));
            float sm = 0.f;
#pragma unroll
            for (int kt = 0; kt < 4; kt++)
#pragma unroll
                for (int r = 0; r < 4; r++) {
                    float e = __expf(S[kt][qt][r] - mx);
                    S[kt][qt][r] = e;
                    sm += e;
                }
            sm += __shfl_xor(sm, 16, 64);
            sm += __shfl_xor(sm, 32, 64);
            rinv[qt] = 1.0f / sm;
        }

#pragma unroll
        for (int qt = 0; qt < 4; qt++)
#pragma unroll
            for (int kt = 0; kt < 4; kt++) {
                unsigned int d0 = ((unsigned int)f2bf(S[kt][qt][1]) << 16) | f2bf(S[kt][qt][0]);
                unsigned int d1 = ((unsigned int)f2bf(S[kt][qt][3]) << 16) | f2bf(S[kt][qt][2]);
                *(uint2*)&Pw[(qt * 16 + l16) * 72 + kt * 16 + quad * 4] = make_uint2(d0, d1);
            }

        bf16x8 vf[2];
#pragma unroll
        for (int ksp = 0; ksp < 2; ksp++)
            vf[ksp] = *(const bf16x8*)&vw[l16 * 72 + ksp * 32 + quad * 8];
#pragma unroll
        for (int qt = 0; qt < 4; qt++) {
            f32x4 O = {0.f, 0.f, 0.f, 0.f};
#pragma unroll
            for (int ksp = 0; ksp < 2; ksp++) {
                bf16x8 pf = *(const bf16x8*)&Pw[(qt * 16 + l16) * 72 + ksp * 32 + quad * 8];
                O = __builtin_amdgcn_mfma_f32_16x16x32_bf16(vf[ksp], pf, O, 0, 0, 0);
            }
            int a = qt * 16 + l16;
            if (a < 49) {
                float ri = rinv[qt];
                unsigned int d0 = ((unsigned int)f2bf(O[1] * ri) << 16) | f2bf(O[0] * ri);
                unsigned int d1 = ((unsigned int)f2bf(O[3] * ri) << 16) | f2bf(O[2] * ri);
                *(uint2*)&ao[(size_t)toks4[qt] * 96 + head * 16 + quad * 4] = make_uint2(d0, d1);
            }
        }
    }
}

// ---------------------------------------------------------------------------
// Final 1x1 conv (96->48) + ReLU via MFMA, LDS-free direct fragments.
// ---------------------------------------------------------------------------
__global__ __launch_bounds__(256) void outconv_mfma(const u16* __restrict__ Th,
        const u16* __restrict__ Woc, const float* __restrict__ ob,
        float* __restrict__ out) {
    int tid = threadIdx.x;
    int w = tid >> 6, lane = tid & 63, quad = lane >> 4, l16 = lane & 15;
    int t0 = blockIdx.x * 128, b = blockIdx.y;
    size_t m0 = (size_t)b * 12544 + t0;

    bf16x8 af[2][3], bfr[3][3];
#pragma unroll
    for (int mi = 0; mi < 2; mi++)
#pragma unroll
        for (int kk = 0; kk < 3; kk++)
            af[mi][kk] = *(const bf16x8*)&Th[(m0 + w * 32 + mi * 16 + l16) * 96 + kk * 32 + quad * 8];
#pragma unroll
    for (int ni = 0; ni < 3; ni++)
#pragma unroll
        for (int kk = 0; kk < 3; kk++)
            bfr[ni][kk] = *(const bf16x8*)&Woc[(size_t)(ni * 16 + l16) * 96 + kk * 32 + quad * 8];

    f32x4 acc[2][3];
#pragma unroll
    for (int mi = 0; mi < 2; mi++)
#pragma unroll
        for (int ni = 0; ni < 3; ni++) acc[mi][ni] = f32x4{0.f, 0.f, 0.f, 0.f};
#pragma unroll
    for (int kk = 0; kk < 3; kk++)
#pragma unroll
        for (int mi = 0; mi < 2; mi++)
#pragma unroll
            for (int ni = 0; ni < 3; ni++)
                acc[mi][ni] = __builtin_amdgcn_mfma_f32_16x16x32_bf16(
                    af[mi][kk], bfr[ni][kk], acc[mi][ni], 0, 0, 0);

#pragma unroll
    for (int mi = 0; mi < 2; mi++)
#pragma unroll
        for (int ni = 0; ni < 3; ni++) {
            int co = ni * 16 + l16;
            float bb = ob[co];
            f32x4 o = {fmaxf(acc[mi][ni][0] + bb, 0.f), fmaxf(acc[mi][ni][1] + bb, 0.f),
                       fmaxf(acc[mi][ni][2] + bb, 0.f), fmaxf(acc[mi][ni][3] + bb, 0.f)};
            *(f32x4*)&out[((size_t)b * 48 + co) * 12544 + t0 + w * 32 + mi * 16 + quad * 4] = o;
        }
}

// ---------------------------------------------------------------------------
extern "C" void kernel_launch(void* const* d_in, const int* in_sizes, int n_in,
                              void* d_out, int out_size, void* d_ws, size_t ws_size,
                              hipStream_t stream) {
    const float* x     = (const float*)d_in[0];
    const float* up_w  = (const float*)d_in[1];
    const float* up_b  = (const float*)d_in[2];
    const float* bn_g  = (const float*)d_in[3];
    const float* bn_b  = (const float*)d_in[4];
    const float* bn_m  = (const float*)d_in[5];
    const float* bn_v  = (const float*)d_in[6];
    const float* n1g   = (const float*)d_in[7];
    const float* n1b   = (const float*)d_in[8];
    const float* qkvw  = (const float*)d_in[9];
    const float* qkvb  = (const float*)d_in[10];
    const float* projw = (const float*)d_in[11];
    const float* projb = (const float*)d_in[12];
    const float* rel   = (const float*)d_in[13];
    const float* n2g   = (const float*)d_in[14];
    const float* n2b   = (const float*)d_in[15];
    const float* f1w   = (const float*)d_in[16];
    const float* f1b   = (const float*)d_in[17];
    const float* f2w   = (const float*)d_in[18];
    const float* f2b   = (const float*)d_in[19];
    const float* outw  = (const float*)d_in[20];
    const float* outb  = (const float*)d_in[21];
    float* out = (float*)d_out;

    char* base = (char*)d_ws;
    float* T  = (float*)base;                       base += (size_t)M_TOK * 96 * 4;
    u16* XBh  = (u16*)base;                         base += (size_t)M_TOK * 96 * 2;
    u16* BIGh = (u16*)base;                         base += (size_t)M_TOK * 384 * 2;
    u16* xT   = (u16*)base;                         base += (size_t)8 * 3136 * 192 * 2;
    u16* Wc   = (u16*)base;                         base += (size_t)16 * 96 * 192 * 2;
    u16* Wh   = (u16*)base;                         base += (size_t)225792 * 2;
    float* BT = (float*)base;
    u16* qkvwh = Wh;
    u16* projwh = Wh + 55296;
    u16* f1wh = Wh + 73728;
    u16* f2wh = Wh + 147456;
    u16* outwh = Wh + 221184;

    prep_kernel<<<1218, 256, 0, stream>>>(qkvw, projw, f1w, f2w, outw, up_w, rel, Wh, Wc, BT);
    transpose_kernel<<<dim3(49, 8), 256, 0, stream>>>(x, xT);
    conv_mfma<<<dim3(49, 4, 8), 256, 0, stream>>>(xT, Wc, up_b, bn_g, bn_b, bn_m, bn_v,
                                                  n1g, n1b, T, XBh);

    for (int blk = 0; blk < 2; blk++) {
        int shift = (blk == 0) ? 0 : 3;
        gemm_act<0><<<dim3(3, M_TOK / 128), 256, 0, stream>>>(
            XBh, qkvwh + blk * 27648, qkvb + blk * 288, BIGh, 288);
        attn_mfma<<<2048, 192, 0, stream>>>(BIGh, BT + (size_t)blk * 98304, XBh, shift);
        gemm_res<1, 96><<<M_TOK / 128, 256, 0, stream>>>(
            XBh, projwh + blk * 9216, projb + blk * 96, T, T,
            n2g + blk * 96, n2b + blk * 96, XBh);
        gemm_act<1><<<dim3(4, M_TOK / 128), 256, 0, stream>>>(
            XBh, f1wh + blk * 36864, f1b + blk * 384, BIGh, 384);
        if (blk == 0) {
            gemm_res<1, 384><<<M_TOK / 128, 256, 0, stream>>>(
                BIGh, f2wh + blk * 36864, f2b + blk * 96, T, T,
                n1g + 96, n1b + 96, XBh);
        } else {
            gemm_res<0, 384><<<M_TOK / 128, 256, 0, stream>>>(
                BIGh, f2wh + blk * 36864, f2b + blk * 96, T, T,
                nullptr, nullptr, XBh);
        }
    }

    outconv_mfma<<<dim3(98, 8), 256, 0, stream>>>(XBh, outwh, outb, out);
}